// Round 1
// baseline (562.697 us; speedup 1.0000x reference)
//
#include <hip/hip_runtime.h>
#include <math.h>

#define IMG_H 1024
#define IMG_W 1024
#define IMG_B 8
// 256 threads * 4 floats = 1024 = one full row per block
#define TPB 256

__device__ __forceinline__ float sigmoidf(float x) {
    return 1.0f / (1.0f + __expf(-x));
}

// u = sigmoid(o * 2), q = 0
__global__ __launch_bounds__(TPB) void k_init(const float* __restrict__ o,
                                              float* __restrict__ u,
                                              float* __restrict__ q) {
    size_t idx = ((size_t)blockIdx.x * TPB + threadIdx.x) * 4;
    float4 o4 = *(const float4*)(o + idx);
    float4 u4;
    u4.x = sigmoidf(o4.x * 2.0f);
    u4.y = sigmoidf(o4.y * 2.0f);
    u4.z = sigmoidf(o4.z * 2.0f);
    u4.w = sigmoidf(o4.w * 2.0f);
    *(float4*)(u + idx) = u4;
    *(float4*)(q + idx) = make_float4(0.f, 0.f, 0.f, 0.f);
}

// q = relu(q - TAU*( (u[y+1]-u[y])*vf1 + (u[x+1]-u[x])*vf0 ))
__global__ __launch_bounds__(TPB) void k_grad(const float* __restrict__ u,
                                              const float* __restrict__ vf,
                                              float* __restrict__ q) {
    __shared__ __align__(16) float su[IMG_W + 4];
    const int row = blockIdx.x & (IMG_H - 1);
    const int x0  = threadIdx.x * 4;
    const size_t base = (size_t)blockIdx.x * IMG_W;  // (b*H + row)*W

    float4 u4 = *(const float4*)(u + base + x0);
    *(float4*)(su + x0) = u4;
    if (threadIdx.x == 0) su[IMG_W] = 0.0f;   // zero pad at x = W

    float4 un4;
    if (row < IMG_H - 1) un4 = *(const float4*)(u + base + IMG_W + x0);
    else                 un4 = make_float4(0.f, 0.f, 0.f, 0.f);

    const size_t vbase = ((size_t)row * IMG_W + x0) * 2;
    float4 vfa = *(const float4*)(vf + vbase);      // vf0[x0],vf1[x0],vf0[x0+1],vf1[x0+1]
    float4 vfb = *(const float4*)(vf + vbase + 4);

    float4 q4 = *(const float4*)(q + base + x0);

    __syncthreads();

    const float uc[4]  = {u4.x, u4.y, u4.z, u4.w};
    const float un[4]  = {un4.x, un4.y, un4.z, un4.w};
    const float v0[4]  = {vfa.x, vfa.z, vfb.x, vfb.z};
    const float v1[4]  = {vfa.y, vfa.w, vfb.y, vfb.w};
    float qq[4]        = {q4.x, q4.y, q4.z, q4.w};

#pragma unroll
    for (int j = 0; j < 4; ++j) {
        float gx = su[x0 + j + 1] - uc[j];
        float gy = un[j] - uc[j];
        float nq = qq[j] - 0.5f * (gy * v1[j] + gx * v0[j]);
        qq[j] = fmaxf(nq, 0.0f);
    }
    *(float4*)(q + base + x0) = make_float4(qq[0], qq[1], qq[2], qq[3]);
}

// Tq = p1[y]-p1[y-1] + p0[x]-p0[x-1], p1=vf1*q, p0=vf0*q
// val = (o - Tq)*2 ; u = sigmoid(val), or out = val on last iter
__global__ __launch_bounds__(TPB) void k_div(const float* __restrict__ q,
                                             const float* __restrict__ vf,
                                             const float* __restrict__ o,
                                             float* uo,   // u buffer == d_out
                                             int last) {
    __shared__ __align__(16) float sp0[IMG_W + 4]; // sp0[i] = p0 at x=i-1; sp0[0]=0
    const int row = blockIdx.x & (IMG_H - 1);
    const int x0  = threadIdx.x * 4;
    const size_t base = (size_t)blockIdx.x * IMG_W;

    float4 q4 = *(const float4*)(q + base + x0);
    const size_t vbase = ((size_t)row * IMG_W + x0) * 2;
    float4 vfa = *(const float4*)(vf + vbase);
    float4 vfb = *(const float4*)(vf + vbase + 4);

    const float v0[4] = {vfa.x, vfa.z, vfb.x, vfb.z};
    const float v1[4] = {vfa.y, vfa.w, vfb.y, vfb.w};
    const float qc[4] = {q4.x, q4.y, q4.z, q4.w};

    float p0[4], p1[4];
#pragma unroll
    for (int j = 0; j < 4; ++j) {
        p0[j] = v0[j] * qc[j];
        p1[j] = v1[j] * qc[j];
    }
    if (threadIdx.x == 0) sp0[0] = 0.0f;  // zero pad at x = -1
#pragma unroll
    for (int j = 0; j < 4; ++j) sp0[x0 + j + 1] = p0[j];

    float p1m[4];
    if (row > 0) {
        float4 qm  = *(const float4*)(q + base - IMG_W + x0);
        float4 vma = *(const float4*)(vf + vbase - 2 * IMG_W);
        float4 vmb = *(const float4*)(vf + vbase - 2 * IMG_W + 4);
        p1m[0] = qm.x * vma.y;
        p1m[1] = qm.y * vma.w;
        p1m[2] = qm.z * vmb.y;
        p1m[3] = qm.w * vmb.w;
    } else {
        p1m[0] = p1m[1] = p1m[2] = p1m[3] = 0.0f;
    }

    float4 o4 = *(const float4*)(o + base + x0);
    const float oc[4] = {o4.x, o4.y, o4.z, o4.w};

    __syncthreads();

    float r[4];
#pragma unroll
    for (int j = 0; j < 4; ++j) {
        float Tq  = p1[j] - p1m[j] + p0[j] - sp0[x0 + j];
        float val = (oc[j] - Tq) * 2.0f;
        r[j] = last ? val : sigmoidf(val);
    }
    *(float4*)(uo + base + x0) = make_float4(r[0], r[1], r[2], r[3]);
}

extern "C" void kernel_launch(void* const* d_in, const int* in_sizes, int n_in,
                              void* d_out, int out_size, void* d_ws, size_t ws_size,
                              hipStream_t stream) {
    const float* o  = (const float*)d_in[0];
    const float* vf = (const float*)d_in[1];
    // nabla_w / div_w (d_in[2], d_in[3]) are compile-time constants, hardcoded.

    float* u = (float*)d_out;          // u lives in d_out (same size/shape)
    float* q = (float*)d_ws;           // 32 MB scratch

    const int nblocks = IMG_B * IMG_H; // 8192

    k_init<<<nblocks, TPB, 0, stream>>>(o, u, q);
    for (int it = 0; it < 10; ++it) {
        k_grad<<<nblocks, TPB, 0, stream>>>(u, vf, q);
        k_div<<<nblocks, TPB, 0, stream>>>(q, vf, o, u, it == 9 ? 1 : 0);
    }
}

// Round 2
// 317.433 us; speedup vs baseline: 1.7727x; 1.7727x over previous
//
#include <hip/hip_runtime.h>
#include <math.h>

#define IMG_H 1024
#define IMG_W 1024
#define IMG_B 8
#define TPB 256                       // 256 thr * 4 floats = one full row
#define RPB 8                         // rows per block band
#define BANDS (IMG_H / RPB)           // 128
#define NBAND_BLOCKS (IMG_B * BANDS)  // 1024

__device__ __forceinline__ float sigmoidf(float x) {
    return 1.0f / (1.0f + __expf(-x));
}

// ---------------------------------------------------------------------------
// K0: q1 = relu(0 - TAU*grad(u0)) with u0 = sigmoid(2*o) computed on the fly.
// One block per 8-row band; u rows staged in 2-row LDS pipeline.
// ---------------------------------------------------------------------------
__global__ __launch_bounds__(TPB) void k_grad0(const float* __restrict__ o,
                                               const float* __restrict__ vf,
                                               float* __restrict__ qout) {
    __shared__ __align__(16) float su[2][IMG_W + 4];
    const int img = blockIdx.x / BANDS;
    const int r0  = (blockIdx.x % BANDS) * RPB;
    const int x0  = threadIdx.x * 4;
    const size_t ibase = (size_t)img * IMG_H * IMG_W;

    float v0p[4], v1p[4];

    for (int y = r0; y <= r0 + RPB; ++y) {
        const int buf = y & 1;
        float v0[4], v1[4];
        const bool act = (y < IMG_H);
        if (act) {
            const size_t rbase = ibase + (size_t)y * IMG_W + x0;
            float4 o4 = *(const float4*)(o + rbase);
            const size_t vbase = ((size_t)y * IMG_W + x0) * 2;
            float4 va = *(const float4*)(vf + vbase);
            float4 vb = *(const float4*)(vf + vbase + 4);
            v0[0]=va.x; v0[1]=va.z; v0[2]=vb.x; v0[3]=vb.z;
            v1[0]=va.y; v1[1]=va.w; v1[2]=vb.y; v1[3]=vb.w;
            su[buf][x0+0] = sigmoidf(o4.x * 2.0f);
            su[buf][x0+1] = sigmoidf(o4.y * 2.0f);
            su[buf][x0+2] = sigmoidf(o4.z * 2.0f);
            su[buf][x0+3] = sigmoidf(o4.w * 2.0f);
        } else {
#pragma unroll
            for (int j = 0; j < 4; ++j) su[buf][x0+j] = 0.0f;
        }
        if (threadIdx.x == 0) su[buf][IMG_W] = 0.0f;  // x zero-pad
        __syncthreads();
        if (y > r0) {
            const int pb = 1 - buf;
            float r[4];
#pragma unroll
            for (int j = 0; j < 4; ++j) {
                float gy = su[buf][x0+j] - su[pb][x0+j];      // u[y]-u[y-1] = gy at row y-1
                float gx = su[pb][x0+j+1] - su[pb][x0+j];
                float nq = -0.5f * (gy * v1p[j] + gx * v0p[j]);  // q_old = 0
                r[j] = fmaxf(nq, 0.0f);
            }
            *(float4*)(qout + ibase + (size_t)(y-1) * IMG_W + x0) =
                make_float4(r[0], r[1], r[2], r[3]);
        }
#pragma unroll
        for (int j = 0; j < 4; ++j) { v0p[j] = v0[j]; v1p[j] = v1[j]; }
        __syncthreads();  // protect su[1-buf] before next-iteration overwrite
    }
}

// ---------------------------------------------------------------------------
// Fused div+grad: reads q_i, recomputes u_i = sigmoid(2*(o - Tq(q_i)))
// row-by-row, writes q_{i+1} = relu(q_i - TAU*grad(u_i).vf).
// u never touches global memory.
// ---------------------------------------------------------------------------
__global__ __launch_bounds__(TPB) void k_fused(const float* __restrict__ qin,
                                               const float* __restrict__ vf,
                                               const float* __restrict__ o,
                                               float* __restrict__ qout) {
    __shared__ __align__(16) float su[2][IMG_W + 4];
    __shared__ __align__(16) float sp0[IMG_W + 4];
    const int img = blockIdx.x / BANDS;
    const int r0  = (blockIdx.x % BANDS) * RPB;
    const int x0  = threadIdx.x * 4;
    const size_t ibase = (size_t)img * IMG_H * IMG_W;

    float p1p[4], qprev[4], v0p[4], v1p[4];

    // prologue: p1 at halo row r0-1 (zero-pad at image top)
    if (r0 > 0) {
        const size_t rbase = ibase + (size_t)(r0 - 1) * IMG_W + x0;
        float4 q4 = *(const float4*)(qin + rbase);
        const size_t vbase = ((size_t)(r0 - 1) * IMG_W + x0) * 2;
        float4 va = *(const float4*)(vf + vbase);
        float4 vb = *(const float4*)(vf + vbase + 4);
        p1p[0] = q4.x * va.y; p1p[1] = q4.y * va.w;
        p1p[2] = q4.z * vb.y; p1p[3] = q4.w * vb.w;
    } else {
        p1p[0] = p1p[1] = p1p[2] = p1p[3] = 0.0f;
    }

    for (int y = r0; y <= r0 + RPB; ++y) {
        const int buf = y & 1;
        float qc[4], v0[4], v1[4], p1[4], p0[4], oc[4];
        const bool act = (y < IMG_H);
        if (act) {
            const size_t rbase = ibase + (size_t)y * IMG_W + x0;
            float4 q4 = *(const float4*)(qin + rbase);
            const size_t vbase = ((size_t)y * IMG_W + x0) * 2;
            float4 va = *(const float4*)(vf + vbase);
            float4 vb = *(const float4*)(vf + vbase + 4);
            float4 o4 = *(const float4*)(o + rbase);
            qc[0]=q4.x; qc[1]=q4.y; qc[2]=q4.z; qc[3]=q4.w;
            v0[0]=va.x; v0[1]=va.z; v0[2]=vb.x; v0[3]=vb.z;
            v1[0]=va.y; v1[1]=va.w; v1[2]=vb.y; v1[3]=vb.w;
            oc[0]=o4.x; oc[1]=o4.y; oc[2]=o4.z; oc[3]=o4.w;
#pragma unroll
            for (int j = 0; j < 4; ++j) {
                p0[j] = v0[j] * qc[j];
                p1[j] = v1[j] * qc[j];
                sp0[x0 + 1 + j] = p0[j];   // sp0[i] holds p0 at x=i-1
            }
            if (threadIdx.x == 0) sp0[0] = 0.0f;  // p0[-1] zero-pad
        }
        __syncthreads();  // sp0 ready
        if (act) {
#pragma unroll
            for (int j = 0; j < 4; ++j) {
                float Tq = p1[j] - p1p[j] + p0[j] - sp0[x0 + j];
                su[buf][x0+j] = sigmoidf((oc[j] - Tq) * 2.0f);
            }
        } else {
#pragma unroll
            for (int j = 0; j < 4; ++j) su[buf][x0+j] = 0.0f;  // u[H] = 0 pad
        }
        if (threadIdx.x == 0) su[buf][IMG_W] = 0.0f;  // x zero-pad
        __syncthreads();  // u row ready; also fences sp0 reads vs next write
        if (y > r0) {
            const int pb = 1 - buf;
            float r[4];
#pragma unroll
            for (int j = 0; j < 4; ++j) {
                float gy = su[buf][x0+j] - su[pb][x0+j];
                float gx = su[pb][x0+j+1] - su[pb][x0+j];
                float nq = qprev[j] - 0.5f * (gy * v1p[j] + gx * v0p[j]);
                r[j] = fmaxf(nq, 0.0f);
            }
            *(float4*)(qout + ibase + (size_t)(y-1) * IMG_W + x0) =
                make_float4(r[0], r[1], r[2], r[3]);
        }
#pragma unroll
        for (int j = 0; j < 4; ++j) {
            p1p[j] = p1[j]; qprev[j] = qc[j]; v0p[j] = v0[j]; v1p[j] = v1[j];
        }
    }
}

// ---------------------------------------------------------------------------
// Final: out = (o - Tq(q10)) * 2   (one row per block)
// ---------------------------------------------------------------------------
__global__ __launch_bounds__(TPB) void k_final(const float* __restrict__ q,
                                               const float* __restrict__ vf,
                                               const float* __restrict__ o,
                                               float* __restrict__ out) {
    __shared__ __align__(16) float sp0[IMG_W + 4];
    const int row = blockIdx.x & (IMG_H - 1);
    const int x0  = threadIdx.x * 4;
    const size_t base = (size_t)blockIdx.x * IMG_W;

    float4 q4 = *(const float4*)(q + base + x0);
    const size_t vbase = ((size_t)row * IMG_W + x0) * 2;
    float4 vfa = *(const float4*)(vf + vbase);
    float4 vfb = *(const float4*)(vf + vbase + 4);

    const float v0[4] = {vfa.x, vfa.z, vfb.x, vfb.z};
    const float v1[4] = {vfa.y, vfa.w, vfb.y, vfb.w};
    const float qc[4] = {q4.x, q4.y, q4.z, q4.w};

    float p0[4], p1[4];
#pragma unroll
    for (int j = 0; j < 4; ++j) {
        p0[j] = v0[j] * qc[j];
        p1[j] = v1[j] * qc[j];
        sp0[x0 + j + 1] = p0[j];
    }
    if (threadIdx.x == 0) sp0[0] = 0.0f;

    float p1m[4];
    if (row > 0) {
        float4 qm  = *(const float4*)(q + base - IMG_W + x0);
        float4 vma = *(const float4*)(vf + vbase - 2 * IMG_W);
        float4 vmb = *(const float4*)(vf + vbase - 2 * IMG_W + 4);
        p1m[0] = qm.x * vma.y; p1m[1] = qm.y * vma.w;
        p1m[2] = qm.z * vmb.y; p1m[3] = qm.w * vmb.w;
    } else {
        p1m[0] = p1m[1] = p1m[2] = p1m[3] = 0.0f;
    }

    float4 o4 = *(const float4*)(o + base + x0);
    const float oc[4] = {o4.x, o4.y, o4.z, o4.w};

    __syncthreads();

    float r[4];
#pragma unroll
    for (int j = 0; j < 4; ++j) {
        float Tq = p1[j] - p1m[j] + p0[j] - sp0[x0 + j];
        r[j] = (oc[j] - Tq) * 2.0f;
    }
    *(float4*)(out + base + x0) = make_float4(r[0], r[1], r[2], r[3]);
}

extern "C" void kernel_launch(void* const* d_in, const int* in_sizes, int n_in,
                              void* d_out, int out_size, void* d_ws, size_t ws_size,
                              hipStream_t stream) {
    const float* o  = (const float*)d_in[0];
    const float* vf = (const float*)d_in[1];

    float* qA = (float*)d_out;  // scratch for odd q_k (final result overwritten at end)
    float* qB = (float*)d_ws;   // even q_k; q_10 lands here

    // q1 -> qA
    k_grad0<<<NBAND_BLOCKS, TPB, 0, stream>>>(o, vf, qA);

    float* cur = qA;
    float* nxt = qB;
    for (int i = 1; i <= 9; ++i) {   // q_{i+1} = F(q_i)
        k_fused<<<NBAND_BLOCKS, TPB, 0, stream>>>(cur, vf, o, nxt);
        float* t = cur; cur = nxt; nxt = t;
    }
    // cur == qB == d_ws holds q_10; write final output to d_out
    k_final<<<IMG_B * IMG_H, TPB, 0, stream>>>(cur, vf, o, (float*)d_out);
}

// Round 5
// 269.379 us; speedup vs baseline: 2.0889x; 1.1784x over previous
//
#include <hip/hip_runtime.h>
#include <math.h>

#define IMG_H 1024
#define IMG_W 1024
#define IMG_B 8
#define TPB 256                    // 256 thr * 4 px = one full row
#define RPB 16                     // output rows per band
#define BANDS (IMG_H / RPB)        // 64
#define NBLK (IMG_B * BANDS)       // 512 blocks = 2/CU

__device__ __forceinline__ float sig2(float x) {   // sigmoid(2x) == sigmoid(x/EPS)
    return 1.0f / (1.0f + __expf(-2.0f * x));
}

// ---------------------------------------------------------------------------
// Depth-2 fused kernel: reads q_i, writes q_{i+2} for rows [r0, r0+RPB).
// Per-row 5-stage pipeline:
//   S1: p0/p1 of q_i row y (+LDS x-shift)      S2: u_i[y] = sig2(o - Tq_i)
//   S3: q'[y-1] (grad of u_i)  + p0'/p1'       S4: u'[y-1] = sig2(o - Tq')
//   S5: q''[y-2] (grad of u') -> global
// All fp32. Halo rows recomputed per band (radius 2).
// ---------------------------------------------------------------------------
__global__ __launch_bounds__(TPB) void k_fused2(const float* __restrict__ qin,
                                                const float* __restrict__ vf,
                                                const float* __restrict__ o,
                                                float* __restrict__ qout) {
    __shared__ __align__(16) float spa[IMG_W + 4];
    __shared__ __align__(16) float su0[2][IMG_W + 4];
    __shared__ __align__(16) float spb[IMG_W + 4];
    __shared__ __align__(16) float su1[2][IMG_W + 4];

    const int img  = blockIdx.x / BANDS;
    const int r0   = (blockIdx.x % BANDS) * RPB;
    const int x0   = threadIdx.x * 4;
    const bool topb = (r0 == 0);
    const size_t ibase = (size_t)img * IMG_H * IMG_W;

    const int ylo  = topb ? 0 : r0 - 2;                  // first step / first loaded row
    const int yhi  = (r0 + RPB + 1 < IMG_H) ? r0 + RPB + 1 : IMG_H - 1;  // last loaded row
    const int yend = r0 + RPB + 1;                       // last step
    const int u_lo = topb ? 0 : r0 - 1;                  // first u_i / q' row

    float qc[4], oc4[4], v0c[4], v1c[4];                 // row y
    float qn[4], on4[4], v0n[4], v1n[4];                 // prefetch row y+1
    float p1prev[4] = {0,0,0,0};                         // p1_i at y-1
    float qz[4], oz4[4], v0z[4], v1z[4];                 // row y-1 inputs
    float v0w[4], v1w[4];                                // vf at row y-2
    float qpz[4], qpw[4];                                // q' at y-1, y-2
    float p0pz[4], p1pz[4];                              // p0'/p1' at y-1
    float p1pprev[4] = {0,0,0,0};                        // p1' at y-2

    // preload first row
    {
        const size_t rb = ibase + (size_t)ylo * IMG_W + x0;
        float4 q4 = *(const float4*)(qin + rb);
        float4 o4 = *(const float4*)(o + rb);
        const size_t vb = ((size_t)ylo * IMG_W + x0) * 2;
        float4 va = *(const float4*)(vf + vb);
        float4 vb4 = *(const float4*)(vf + vb + 4);
        qc[0]=q4.x; qc[1]=q4.y; qc[2]=q4.z; qc[3]=q4.w;
        oc4[0]=o4.x; oc4[1]=o4.y; oc4[2]=o4.z; oc4[3]=o4.w;
        v0c[0]=va.x; v0c[1]=va.z; v0c[2]=vb4.x; v0c[3]=vb4.z;
        v1c[0]=va.y; v1c[1]=va.w; v1c[2]=vb4.y; v1c[3]=vb4.w;
    }

    for (int y = ylo; y <= yend; ++y) {
        // prefetch row y+1
        if (y + 1 <= yhi) {
            const size_t rb = ibase + (size_t)(y + 1) * IMG_W + x0;
            float4 q4 = *(const float4*)(qin + rb);
            float4 o4 = *(const float4*)(o + rb);
            const size_t vb = ((size_t)(y + 1) * IMG_W + x0) * 2;
            float4 va = *(const float4*)(vf + vb);
            float4 vb4 = *(const float4*)(vf + vb + 4);
            qn[0]=q4.x; qn[1]=q4.y; qn[2]=q4.z; qn[3]=q4.w;
            on4[0]=o4.x; on4[1]=o4.y; on4[2]=o4.z; on4[3]=o4.w;
            v0n[0]=va.x; v0n[1]=va.z; v0n[2]=vb4.x; v0n[3]=vb4.z;
            v1n[0]=va.y; v1n[1]=va.w; v1n[2]=vb4.y; v1n[3]=vb4.w;
        } else {
#pragma unroll
            for (int j = 0; j < 4; ++j) { qn[j]=0.f; on4[j]=0.f; v0n[j]=0.f; v1n[j]=0.f; }
        }

        // ---- S1: p0/p1 of q_i row y ----
        float p0c[4], p1c[4];
        const bool have_y = (y <= yhi);
        if (have_y) {
#pragma unroll
            for (int j = 0; j < 4; ++j) {
                p0c[j] = v0c[j] * qc[j];
                p1c[j] = v1c[j] * qc[j];
                spa[x0 + 1 + j] = p0c[j];
            }
            if (threadIdx.x == 0) spa[0] = 0.0f;
        } else {
#pragma unroll
            for (int j = 0; j < 4; ++j) { p0c[j] = 0.f; p1c[j] = 0.f; }
        }
        __syncthreads();                                  // S1 barrier

        // ---- S2: u_i[y] ----
        const int buf0 = y & 1;
        if (y >= u_lo) {
            if (y <= IMG_H - 1) {
#pragma unroll
                for (int j = 0; j < 4; ++j) {
                    float Tq = p1c[j] - p1prev[j] + p0c[j] - spa[x0 + j];
                    su0[buf0][x0 + j] = sig2(oc4[j] - Tq);
                }
            } else {
#pragma unroll
                for (int j = 0; j < 4; ++j) su0[buf0][x0 + j] = 0.0f;
            }
            if (threadIdx.x == 0) su0[buf0][IMG_W] = 0.0f;
        }
        __syncthreads();                                  // S2 barrier

        // ---- S3: q'[z], z = y-1 ----
        const int z = y - 1;
        const bool s3 = (z >= u_lo) && (z <= r0 + RPB) && (z <= IMG_H - 1);
        if (s3) {
            const int zb = z & 1;
#pragma unroll
            for (int j = 0; j < 4; ++j) {
                float gy = su0[buf0][x0 + j] - su0[zb][x0 + j];
                float gx = su0[zb][x0 + j + 1] - su0[zb][x0 + j];
                qpz[j] = fmaxf(qz[j] - 0.5f * (gy * v1z[j] + gx * v0z[j]), 0.0f);
            }
#pragma unroll
            for (int j = 0; j < 4; ++j) {
                p0pz[j] = v0z[j] * qpz[j];
                p1pz[j] = v1z[j] * qpz[j];
                spb[x0 + 1 + j] = p0pz[j];
            }
            if (threadIdx.x == 0) spb[0] = 0.0f;
        }
        __syncthreads();                                  // S3 barrier

        // ---- S4: u'[z] ----
        if (z >= r0 && z <= r0 + RPB) {
            const int zb = z & 1;
            if (z <= IMG_H - 1) {
#pragma unroll
                for (int j = 0; j < 4; ++j) {
                    float Tq = p1pz[j] - p1pprev[j] + p0pz[j] - spb[x0 + j];
                    su1[zb][x0 + j] = sig2(oz4[j] - Tq);
                }
            } else {
#pragma unroll
                for (int j = 0; j < 4; ++j) su1[zb][x0 + j] = 0.0f;
            }
            if (threadIdx.x == 0) su1[zb][IMG_W] = 0.0f;
        }
        __syncthreads();                                  // S4 barrier

        // ---- S5: q''[w], w = y-2 -> global ----
        const int w = y - 2;
        if (w >= r0 && w <= r0 + RPB - 1) {
            const int wb = w & 1, wb1 = 1 - wb;
            float r[4];
#pragma unroll
            for (int j = 0; j < 4; ++j) {
                float gy = su1[wb1][x0 + j] - su1[wb][x0 + j];
                float gx = su1[wb][x0 + j + 1] - su1[wb][x0 + j];
                r[j] = fmaxf(qpw[j] - 0.5f * (gy * v1w[j] + gx * v0w[j]), 0.0f);
            }
            *(float4*)(qout + ibase + (size_t)w * IMG_W + x0) =
                make_float4(r[0], r[1], r[2], r[3]);
        }

        // ---- rotate ----
#pragma unroll
        for (int j = 0; j < 4; ++j) {
            p1prev[j] = p1c[j];
            v0w[j] = v0z[j]; v1w[j] = v1z[j];
            qz[j] = qc[j]; oz4[j] = oc4[j]; v0z[j] = v0c[j]; v1z[j] = v1c[j];
            qc[j] = qn[j]; oc4[j] = on4[j]; v0c[j] = v0n[j]; v1c[j] = v1n[j];
        }
        if (s3) {
#pragma unroll
            for (int j = 0; j < 4; ++j) { qpw[j] = qpz[j]; p1pprev[j] = p1pz[j]; }
        }
    }
}

// ---------------------------------------------------------------------------
// Init depth-2: u0 = sig2(o) directly (q0 = 0), writes q2.
// ---------------------------------------------------------------------------
__global__ __launch_bounds__(TPB) void k_init2(const float* __restrict__ o,
                                               const float* __restrict__ vf,
                                               float* __restrict__ qout) {
    __shared__ __align__(16) float su0[2][IMG_W + 4];
    __shared__ __align__(16) float spb[IMG_W + 4];
    __shared__ __align__(16) float su1[2][IMG_W + 4];

    const int img  = blockIdx.x / BANDS;
    const int r0   = (blockIdx.x % BANDS) * RPB;
    const int x0   = threadIdx.x * 4;
    const bool topb = (r0 == 0);
    const size_t ibase = (size_t)img * IMG_H * IMG_W;

    const int u_lo = topb ? 0 : r0 - 1;
    const int ylo  = u_lo;
    const int yhi  = (r0 + RPB + 1 < IMG_H) ? r0 + RPB + 1 : IMG_H - 1;
    const int yend = r0 + RPB + 1;

    float oc4[4], v0c[4], v1c[4];
    float on4[4], v0n[4], v1n[4];
    float oz4[4], v0z[4], v1z[4];
    float v0w[4], v1w[4];
    float qpz[4], qpw[4];
    float p0pz[4], p1pz[4];
    float p1pprev[4] = {0,0,0,0};

    {
        const size_t rb = ibase + (size_t)ylo * IMG_W + x0;
        float4 o4 = *(const float4*)(o + rb);
        const size_t vb = ((size_t)ylo * IMG_W + x0) * 2;
        float4 va = *(const float4*)(vf + vb);
        float4 vb4 = *(const float4*)(vf + vb + 4);
        oc4[0]=o4.x; oc4[1]=o4.y; oc4[2]=o4.z; oc4[3]=o4.w;
        v0c[0]=va.x; v0c[1]=va.z; v0c[2]=vb4.x; v0c[3]=vb4.z;
        v1c[0]=va.y; v1c[1]=va.w; v1c[2]=vb4.y; v1c[3]=vb4.w;
    }

    for (int y = ylo; y <= yend; ++y) {
        if (y + 1 <= yhi) {
            const size_t rb = ibase + (size_t)(y + 1) * IMG_W + x0;
            float4 o4 = *(const float4*)(o + rb);
            const size_t vb = ((size_t)(y + 1) * IMG_W + x0) * 2;
            float4 va = *(const float4*)(vf + vb);
            float4 vb4 = *(const float4*)(vf + vb + 4);
            on4[0]=o4.x; on4[1]=o4.y; on4[2]=o4.z; on4[3]=o4.w;
            v0n[0]=va.x; v0n[1]=va.z; v0n[2]=vb4.x; v0n[3]=vb4.z;
            v1n[0]=va.y; v1n[1]=va.w; v1n[2]=vb4.y; v1n[3]=vb4.w;
        } else {
#pragma unroll
            for (int j = 0; j < 4; ++j) { on4[j]=0.f; v0n[j]=0.f; v1n[j]=0.f; }
        }

        // u0[y] = sig2(o[y])
        const int buf0 = y & 1;
        if (y <= IMG_H - 1) {
#pragma unroll
            for (int j = 0; j < 4; ++j) su0[buf0][x0 + j] = sig2(oc4[j]);
        } else {
#pragma unroll
            for (int j = 0; j < 4; ++j) su0[buf0][x0 + j] = 0.0f;
        }
        if (threadIdx.x == 0) su0[buf0][IMG_W] = 0.0f;
        __syncthreads();

        // q1[z] = relu(-0.5*grad.u0)
        const int z = y - 1;
        const bool s3 = (z >= u_lo) && (z <= r0 + RPB) && (z <= IMG_H - 1);
        if (s3) {
            const int zb = z & 1;
#pragma unroll
            for (int j = 0; j < 4; ++j) {
                float gy = su0[buf0][x0 + j] - su0[zb][x0 + j];
                float gx = su0[zb][x0 + j + 1] - su0[zb][x0 + j];
                qpz[j] = fmaxf(-0.5f * (gy * v1z[j] + gx * v0z[j]), 0.0f);
            }
#pragma unroll
            for (int j = 0; j < 4; ++j) {
                p0pz[j] = v0z[j] * qpz[j];
                p1pz[j] = v1z[j] * qpz[j];
                spb[x0 + 1 + j] = p0pz[j];
            }
            if (threadIdx.x == 0) spb[0] = 0.0f;
        }
        __syncthreads();

        // u1[z]
        if (z >= r0 && z <= r0 + RPB) {
            const int zb = z & 1;
            if (z <= IMG_H - 1) {
#pragma unroll
                for (int j = 0; j < 4; ++j) {
                    float Tq = p1pz[j] - p1pprev[j] + p0pz[j] - spb[x0 + j];
                    su1[zb][x0 + j] = sig2(oz4[j] - Tq);
                }
            } else {
#pragma unroll
                for (int j = 0; j < 4; ++j) su1[zb][x0 + j] = 0.0f;
            }
            if (threadIdx.x == 0) su1[zb][IMG_W] = 0.0f;
        }
        __syncthreads();

        // q2[w] -> global
        const int w = y - 2;
        if (w >= r0 && w <= r0 + RPB - 1) {
            const int wb = w & 1, wb1 = 1 - wb;
            float r[4];
#pragma unroll
            for (int j = 0; j < 4; ++j) {
                float gy = su1[wb1][x0 + j] - su1[wb][x0 + j];
                float gx = su1[wb][x0 + j + 1] - su1[wb][x0 + j];
                r[j] = fmaxf(qpw[j] - 0.5f * (gy * v1w[j] + gx * v0w[j]), 0.0f);
            }
            *(float4*)(qout + ibase + (size_t)w * IMG_W + x0) =
                make_float4(r[0], r[1], r[2], r[3]);
        }

#pragma unroll
        for (int j = 0; j < 4; ++j) {
            v0w[j] = v0z[j]; v1w[j] = v1z[j];
            oz4[j] = oc4[j]; v0z[j] = v0c[j]; v1z[j] = v1c[j];
            oc4[j] = on4[j]; v0c[j] = v0n[j]; v1c[j] = v1n[j];
        }
        if (s3) {
#pragma unroll
            for (int j = 0; j < 4; ++j) { qpw[j] = qpz[j]; p1pprev[j] = p1pz[j]; }
        }
    }
}

// ---------------------------------------------------------------------------
// Final: out = 2*(o - Tq(q10)). One row per block. (Round-2 verified.)
// ---------------------------------------------------------------------------
__global__ __launch_bounds__(TPB) void k_final(const float* __restrict__ q,
                                               const float* __restrict__ vf,
                                               const float* __restrict__ o,
                                               float* __restrict__ out) {
    __shared__ __align__(16) float sp0[IMG_W + 4];
    const int row = blockIdx.x & (IMG_H - 1);
    const int x0  = threadIdx.x * 4;
    const size_t base = (size_t)blockIdx.x * IMG_W;

    float4 q4 = *(const float4*)(q + base + x0);
    const size_t vbase = ((size_t)row * IMG_W + x0) * 2;
    float4 vfa = *(const float4*)(vf + vbase);
    float4 vfb = *(const float4*)(vf + vbase + 4);

    const float v0[4] = {vfa.x, vfa.z, vfb.x, vfb.z};
    const float v1[4] = {vfa.y, vfa.w, vfb.y, vfb.w};
    const float qc[4] = {q4.x, q4.y, q4.z, q4.w};

    float p0[4], p1[4];
#pragma unroll
    for (int j = 0; j < 4; ++j) {
        p0[j] = v0[j] * qc[j];
        p1[j] = v1[j] * qc[j];
        sp0[x0 + j + 1] = p0[j];
    }
    if (threadIdx.x == 0) sp0[0] = 0.0f;

    float p1m[4];
    if (row > 0) {
        float4 qm  = *(const float4*)(q + base - IMG_W + x0);
        float4 vma = *(const float4*)(vf + vbase - 2 * IMG_W);
        float4 vmb = *(const float4*)(vf + vbase - 2 * IMG_W + 4);
        p1m[0] = qm.x * vma.y; p1m[1] = qm.y * vma.w;
        p1m[2] = qm.z * vmb.y; p1m[3] = qm.w * vmb.w;
    } else {
        p1m[0] = p1m[1] = p1m[2] = p1m[3] = 0.0f;
    }

    float4 o4 = *(const float4*)(o + base + x0);
    const float oc[4] = {o4.x, o4.y, o4.z, o4.w};

    __syncthreads();

    float r[4];
#pragma unroll
    for (int j = 0; j < 4; ++j) {
        float Tq = p1[j] - p1m[j] + p0[j] - sp0[x0 + j];
        r[j] = 2.0f * (oc[j] - Tq);
    }
    *(float4*)(out + base + x0) = make_float4(r[0], r[1], r[2], r[3]);
}

extern "C" void kernel_launch(void* const* d_in, const int* in_sizes, int n_in,
                              void* d_out, int out_size, void* d_ws, size_t ws_size,
                              hipStream_t stream) {
    const float* o  = (const float*)d_in[0];
    const float* vf = (const float*)d_in[1];

    float* qA = (float*)d_ws;    // q2, q6, q10
    float* qB = (float*)d_out;   // q4, q8 (overwritten by final output)

    k_init2 <<<NBLK, TPB, 0, stream>>>(o, vf, qA);        // q2 -> A
    k_fused2<<<NBLK, TPB, 0, stream>>>(qA, vf, o, qB);    // q4 -> B
    k_fused2<<<NBLK, TPB, 0, stream>>>(qB, vf, o, qA);    // q6 -> A
    k_fused2<<<NBLK, TPB, 0, stream>>>(qA, vf, o, qB);    // q8 -> B
    k_fused2<<<NBLK, TPB, 0, stream>>>(qB, vf, o, qA);    // q10 -> A
    k_final <<<IMG_B * IMG_H, TPB, 0, stream>>>(qA, vf, o, (float*)d_out);
}